// Round 1
// baseline (348.075 us; speedup 1.0000x reference)
//
#include <hip/hip_runtime.h>
#include <math.h>

// Problem constants (fixed by the reference)
#define BATCH 65536
#define DIM 128
#define NBAS 6
#define OUTW 896              // DIM*NBAS + DIM
#define ROWS_PER_TILE 64
#define LDS_STRIDE 68         // pad: 16B-aligned b128 reads, breaks pow2 store conflicts

// ---------------------------------------------------------------------------
// Kernel 1: S = sigmoid(W), 128x128 into workspace. Trivial.
// ---------------------------------------------------------------------------
__global__ __launch_bounds__(256) void sigmoid_k(const float* __restrict__ W,
                                                 float* __restrict__ S) {
    int t = blockIdx.x * 256 + threadIdx.x;
    float w = W[t];
    S[t] = 1.0f / (1.0f + expf(-w));
}

// ---------------------------------------------------------------------------
// Branch-free Cox-de Boor, degree 3, uniform knots on [-1,1], 10 knots.
// All denominators are d*h > 0 so the reference's where() guards are no-ops.
// Reciprocals 4.5, 2.25, 1.5 are exact binary floats.
// ---------------------------------------------------------------------------
__device__ __forceinline__ void basis6(float x, float* __restrict__ r) {
    const float h = 2.0f / 9.0f;
    float xc = fminf(fmaxf(x, -1.0f), 1.0f - 1e-6f);
    float B0[9];
#pragma unroll
    for (int t = 0; t < 9; ++t) {
        float k0 = -1.0f + (float)t * h;
        float k1 = -1.0f + (float)(t + 1) * h;
        B0[t] = (xc >= k0 && xc < k1) ? 1.0f : 0.0f;
    }
    float B1[8];
#pragma unroll
    for (int t = 0; t < 8; ++t) {
        float k0 = -1.0f + (float)t * h;
        float k2 = -1.0f + (float)(t + 2) * h;
        B1[t] = (xc - k0) * 4.5f * B0[t] + (k2 - xc) * 4.5f * B0[t + 1];
    }
    float B2[7];
#pragma unroll
    for (int t = 0; t < 7; ++t) {
        float k0 = -1.0f + (float)t * h;
        float k3 = -1.0f + (float)(t + 3) * h;
        B2[t] = (xc - k0) * 2.25f * B1[t] + (k3 - xc) * 2.25f * B1[t + 1];
    }
#pragma unroll
    for (int t = 0; t < 6; ++t) {
        float k0 = -1.0f + (float)t * h;
        float k4 = -1.0f + (float)(t + 4) * h;
        r[t] = (xc - k0) * 1.5f * B2[t] + (k4 - xc) * 1.5f * B2[t + 1];
    }
}

// ---------------------------------------------------------------------------
// Main fused kernel. One block = one 64-row tile (1024 blocks total, 4/CU).
// Phase A: stream x (float4), write basis (6x float4/thread, contiguous),
//          stage x^2 transposed into LDS.
// Phase B: 64x128 GEMM vs S (L2-resident); 8 rows x 4 cols per thread.
// ---------------------------------------------------------------------------
__global__ __launch_bounds__(256, 4) void kan_main(const float* __restrict__ X,
                                                   const float* __restrict__ S,
                                                   float* __restrict__ out) {
    __shared__ __align__(16) float xsqT[DIM * LDS_STRIDE];  // [i][r], 34.8 KB

    const int tid = threadIdx.x;
    const int row0 = blockIdx.x * ROWS_PER_TILE;

    // ---------------- Phase A ----------------
    const float4* X4 = (const float4*)(X + (size_t)row0 * DIM);
#pragma unroll
    for (int k = 0; k < 8; ++k) {
        int e4 = k * 256 + tid;      // float4 index in tile, 0..2047
        int e = e4 * 4;              // element index in tile
        int r = e >> 7;              // row within tile (0..63)
        int i = e & 127;             // feature (multiple of 4)
        float4 xv = X4[e4];

        xsqT[(i + 0) * LDS_STRIDE + r] = xv.x * xv.x;
        xsqT[(i + 1) * LDS_STRIDE + r] = xv.y * xv.y;
        xsqT[(i + 2) * LDS_STRIDE + r] = xv.z * xv.z;
        xsqT[(i + 3) * LDS_STRIDE + r] = xv.w * xv.w;

        float res[24];
        basis6(xv.x, res + 0);
        basis6(xv.y, res + 6);
        basis6(xv.z, res + 12);
        basis6(xv.w, res + 18);

        float4* o4 = (float4*)(out + (size_t)(row0 + r) * OUTW + i * NBAS);
#pragma unroll
        for (int q = 0; q < 6; ++q) {
            o4[q] = make_float4(res[q * 4 + 0], res[q * 4 + 1],
                                res[q * 4 + 2], res[q * 4 + 3]);
        }
    }
    __syncthreads();

    // ---------------- Phase B ----------------
    const int c = tid & 31;          // col group: cols 4c..4c+3
    const int rg = tid >> 5;         // row group: rows rg*8..rg*8+7
    const int r0 = rg * 8;

    float acc[8][4];
#pragma unroll
    for (int rr = 0; rr < 8; ++rr)
#pragma unroll
        for (int q = 0; q < 4; ++q) acc[rr][q] = 0.0f;

    const float4* S4 = (const float4*)S;
#pragma unroll 4
    for (int i = 0; i < DIM; ++i) {
        float4 s = S4[i * 32 + c];                         // L2-resident, coalesced
        const float4* xr4 = (const float4*)&xsqT[i * LDS_STRIDE + r0];
        float4 xa = xr4[0];                                // broadcast b128 reads
        float4 xb = xr4[1];
        float xr[8] = {xa.x, xa.y, xa.z, xa.w, xb.x, xb.y, xb.z, xb.w};
#pragma unroll
        for (int rr = 0; rr < 8; ++rr) {
#pragma unroll
            for (int q = 0; q < 4; ++q) {
                float sv = (q == 0) ? s.x : (q == 1) ? s.y : (q == 2) ? s.z : s.w;
                acc[rr][q] = fmaf(xr[rr], sv, acc[rr][q]);
            }
        }
    }

#pragma unroll
    for (int rr = 0; rr < 8; ++rr) {
        float4* o = (float4*)(out + (size_t)(row0 + r0 + rr) * OUTW + DIM * NBAS + 4 * c);
        *o = make_float4(acc[rr][0], acc[rr][1], acc[rr][2], acc[rr][3]);
    }
}

// ---------------------------------------------------------------------------
extern "C" void kernel_launch(void* const* d_in, const int* in_sizes, int n_in,
                              void* d_out, int out_size, void* d_ws, size_t ws_size,
                              hipStream_t stream) {
    const float* X = (const float*)d_in[0];
    const float* W = (const float*)d_in[1];
    float* out = (float*)d_out;
    float* S = (float*)d_ws;   // 64 KB scratch for sigmoid(W)

    sigmoid_k<<<(DIM * DIM) / 256, 256, 0, stream>>>(W, S);
    kan_main<<<BATCH / ROWS_PER_TILE, 256, 0, stream>>>(X, S, out);
}